// Round 1
// baseline (1022.415 us; speedup 1.0000x reference)
//
#include <hip/hip_runtime.h>

#define S_LEN 512
#define BSZ 8
#define NH 8
#define HD 64
#define IN_DIM 512
#define PROJ 2576   // NH*(5*HD+2)
#define SEG 322     // per-head: 5*64+2

typedef __attribute__((ext_vector_type(8))) __bf16 bf16x8;
typedef __attribute__((ext_vector_type(4))) float f32x4;

static __device__ __forceinline__ unsigned short f2bf(float f) {
  unsigned u = __float_as_uint(f);
  unsigned r = (u + 0x7fffu + ((u >> 16) & 1u)) >> 16;
  return (unsigned short)r;
}
static __device__ __forceinline__ float bf2f(unsigned short s) {
  return __uint_as_float(((unsigned)s) << 16);
}

// ---------------- LayerNorm: x (4096x512 f32) -> normed bf16 ----------------
__global__ __launch_bounds__(256) void ln_kernel(const float* __restrict__ x,
                                                 const float* __restrict__ gamma,
                                                 const float* __restrict__ beta,
                                                 unsigned short* __restrict__ out) {
  int wave = threadIdx.x >> 6, lane = threadIdx.x & 63;
  int row = blockIdx.x * 4 + wave;
  const float* xr = x + (size_t)row * IN_DIM + lane * 8;
  float4 a = *(const float4*)xr;
  float4 b = *(const float4*)(xr + 4);
  float vals[8] = {a.x, a.y, a.z, a.w, b.x, b.y, b.z, b.w};
  float s = 0.f, ss = 0.f;
#pragma unroll
  for (int i = 0; i < 8; i++) { s += vals[i]; ss += vals[i] * vals[i]; }
#pragma unroll
  for (int o = 32; o; o >>= 1) { s += __shfl_xor(s, o); ss += __shfl_xor(ss, o); }
  float mu = s * (1.f / 512.f);
  float var = ss * (1.f / 512.f) - mu * mu;
  float rstd = rsqrtf(var + 1e-5f);
  const float* g = gamma + lane * 8;
  const float* be = beta + lane * 8;
  float4 g1 = *(const float4*)g, g2 = *(const float4*)(g + 4);
  float4 b1 = *(const float4*)be, b2 = *(const float4*)(be + 4);
  float gs[8] = {g1.x, g1.y, g1.z, g1.w, g2.x, g2.y, g2.z, g2.w};
  float bs[8] = {b1.x, b1.y, b1.z, b1.w, b2.x, b2.y, b2.z, b2.w};
  union { unsigned short u[8]; uint4 v; } pk;
#pragma unroll
  for (int i = 0; i < 8; i++) pk.u[i] = f2bf((vals[i] - mu) * rstd * gs[i] + bs[i]);
  *(uint4*)(out + (size_t)row * IN_DIM + lane * 8) = pk.v;
}

// ---------------- generic f32 -> bf16 cast ----------------
__global__ void cast_kernel(const float* __restrict__ in, unsigned short* __restrict__ out, int n) {
  int i = blockIdx.x * blockDim.x + threadIdx.x;
  int st = gridDim.x * blockDim.x;
  for (; i < n; i += st) out[i] = f2bf(in[i]);
}

// ---------------- GEMM: C[m][n] = sum_k A[m][k]*B[n][k] (both bf16, K-contig) ----------------
// 64x64 block tile, BK=32, 256 threads (4 waves x 16-row strips), mfma 16x16x32 bf16.
template <int BF16_OUT, int RESID>
__global__ __launch_bounds__(256) void gemm_bt(const unsigned short* __restrict__ A,
                                               const unsigned short* __restrict__ B,
                                               void* __restrict__ Cout,
                                               const float* __restrict__ resid,
                                               int M, int N, int K) {
  __shared__ __align__(16) unsigned short As[64][40];
  __shared__ __align__(16) unsigned short Bs[64][40];
  int tid = threadIdx.x;
  int lane = tid & 63, wave = tid >> 6;
  int m0 = blockIdx.y * 64, n0 = blockIdx.x * 64;
  int srow = tid >> 2, skq = (tid & 3) * 8;
  const unsigned short* Ap = A + (size_t)(m0 + srow) * K + skq;
  const unsigned short* Bp = B + (size_t)(n0 + srow) * K + skq;
  bool bvalid = (n0 + srow) < N;
  f32x4 zero = {0.f, 0.f, 0.f, 0.f};
  f32x4 acc[4];
#pragma unroll
  for (int nt = 0; nt < 4; nt++) acc[nt] = zero;
  int q = lane >> 4, m16 = lane & 15;
  for (int k0 = 0; k0 < K; k0 += 32) {
    uint4 av = *(const uint4*)(Ap + k0);
    uint4 bz = {0u, 0u, 0u, 0u};
    uint4 bv = bvalid ? *(const uint4*)(Bp + k0) : bz;
    *(uint4*)&As[srow][skq] = av;
    *(uint4*)&Bs[srow][skq] = bv;
    __syncthreads();
    bf16x8 af = *(const bf16x8*)&As[wave * 16 + m16][q * 8];
#pragma unroll
    for (int nt = 0; nt < 4; nt++) {
      bf16x8 bfv = *(const bf16x8*)&Bs[nt * 16 + m16][q * 8];
      acc[nt] = __builtin_amdgcn_mfma_f32_16x16x32_bf16(af, bfv, acc[nt], 0, 0, 0);
    }
    __syncthreads();
  }
  int rbase = q * 4;
#pragma unroll
  for (int nt = 0; nt < 4; nt++) {
#pragma unroll
    for (int rr = 0; rr < 4; rr++) {
      int gm = m0 + wave * 16 + rbase + rr;
      int gn = n0 + nt * 16 + m16;
      if (gn < N) {
        float v = acc[nt][rr];
        if (BF16_OUT) {
          ((unsigned short*)Cout)[(size_t)gm * N + gn] = f2bf(v);
        } else {
          float o = v;
          if (RESID) o += resid[(size_t)gm * N + gn];
          ((float*)Cout)[(size_t)gm * N + gn] = o;
        }
      }
    }
  }
}

// ---------------- fused activation + double scan ----------------
// One block per (b,h). 256 threads: thread (r = tid/4, c = tid&3) owns cols [16c,16c+16)
// of row r of both fast-weight matrices W (delta rule) and R (recurrent delta rule).
__global__ __launch_bounds__(256) void scan_kernel(const unsigned short* __restrict__ qkvb,
                                                   unsigned short* __restrict__ hs) {
  int bh = blockIdx.x;
  int b = bh >> 3, hh = bh & 7;
  int tid = threadIdx.x;
  int lane = tid & 63, wave = tid >> 6;
  int r = tid >> 2, c = tid & 3;

  __shared__ float sl[2][324];  // raw->activated slice, double buffered
  __shared__ float e_lds[64];
  __shared__ float red[2][4];

  float Wrow[16], Rrow[16];
#pragma unroll
  for (int i = 0; i < 16; i++) { Wrow[i] = 0.f; Rrow[i] = 0.f; }
  float h_r = 0.f;

  const unsigned short* src = qkvb + (size_t)b * PROJ + hh * SEG;
  const size_t tstride = (size_t)BSZ * PROJ;  // elements per timestep

  // stage t=0 directly
  if (tid < 161) {
    unsigned w0 = *(const unsigned*)(src + 2 * tid);
    sl[0][2 * tid] = bf2f((unsigned short)(w0 & 0xffff));
    sl[0][2 * tid + 1] = bf2f((unsigned short)(w0 >> 16));
  }
  unsigned pf1 = 0, pf2 = 0;
  if (tid < 161) pf1 = *(const unsigned*)(src + tstride + 2 * tid);

  for (int t = 0; t < S_LEN; t++) {
    int buf = t & 1;
    if (t + 2 < S_LEN && tid < 161)
      pf2 = *(const unsigned*)(src + (size_t)(t + 2) * tstride + 2 * tid);

    __syncthreads();  // raw slice for step t visible
    // in-place activations: softmax(q), softmax(k), softmax(rk); sigmoid(beta, rbeta)
    if (wave < 3) {
      int off = (wave == 0) ? 0 : (wave == 1 ? 64 : 192);
      float v = sl[buf][off + lane];
      float m = v;
#pragma unroll
      for (int o = 32; o; o >>= 1) m = fmaxf(m, __shfl_xor(m, o));
      float e = __expf(v - m);
      float s2 = e;
#pragma unroll
      for (int o = 32; o; o >>= 1) s2 += __shfl_xor(s2, o);
      sl[buf][off + lane] = e / s2;
    } else if (lane < 2) {
      float v = sl[buf][320 + lane];
      sl[buf][320 + lane] = 1.f / (1.f + __expf(-v));
    }
    __syncthreads();

    const float* sq = sl[buf];
    const float* sk = sl[buf] + 64;
    const float* sv = sl[buf] + 128;
    const float* srk = sl[buf] + 192;
    const float* srv = sl[buf] + 256;
    float beta = sl[buf][320], rbeta = sl[buf][321];

    // ---- fast weight memory: v_old = W k; W += beta*(v - v_old) k^T; z = W q ----
    float kreg[16], qreg[16];
    float vold = 0.f;
#pragma unroll
    for (int i = 0; i < 16; i++) {
      kreg[i] = sk[16 * c + i];
      qreg[i] = sq[16 * c + i];
      vold += Wrow[i] * kreg[i];
    }
    vold += __shfl_xor(vold, 1);
    vold += __shfl_xor(vold, 2);
    float coef = beta * (sv[r] - vold);
    float z = 0.f;
#pragma unroll
    for (int i = 0; i < 16; i++) {
      Wrow[i] += coef * kreg[i];
      z += Wrow[i] * qreg[i];
    }
    z += __shfl_xor(z, 1);
    z += __shfl_xor(z, 2);

    // ---- softmax over previous h (64 rows, spread 16 per wave, x4 replicated) ----
    float m = h_r;
#pragma unroll
    for (int o = 32; o; o >>= 1) m = fmaxf(m, __shfl_xor(m, o));
    if (lane == 0) red[0][wave] = m;
    __syncthreads();
    m = fmaxf(fmaxf(red[0][0], red[0][1]), fmaxf(red[0][2], red[0][3]));
    float eh = __expf(h_r - m);
    float ps = (c == 0) ? eh : 0.f;
#pragma unroll
    for (int o = 32; o; o >>= 1) ps += __shfl_xor(ps, o);
    if (lane == 0) red[1][wave] = ps;
    if (c == 0) e_lds[r] = eh;
    __syncthreads();
    float ssum = red[1][0] + red[1][1] + red[1][2] + red[1][3];

    // ---- fast rnn: rv_old = R rk; R += rbeta*(rv - rv_old) rk^T; h = z + R qh ----
    float rkreg[16];
    float rvold = 0.f;
#pragma unroll
    for (int i = 0; i < 16; i++) {
      rkreg[i] = srk[16 * c + i];
      rvold += Rrow[i] * rkreg[i];
    }
    rvold += __shfl_xor(rvold, 1);
    rvold += __shfl_xor(rvold, 2);
    float rcoef = rbeta * (srv[r] - rvold);
    float hp = 0.f;
#pragma unroll
    for (int i = 0; i < 16; i++) {
      Rrow[i] += rcoef * rkreg[i];
      hp += Rrow[i] * e_lds[16 * c + i];
    }
    hp += __shfl_xor(hp, 1);
    hp += __shfl_xor(hp, 2);
    h_r = z + hp / ssum;

    if (c == 0) hs[(size_t)(t * BSZ + b) * 512 + hh * 64 + r] = f2bf(h_r);

    // write prefetched raw slice for t+1 into the other buffer
    if (t + 1 < S_LEN && tid < 161) {
      sl[buf ^ 1][2 * tid] = bf2f((unsigned short)(pf1 & 0xffff));
      sl[buf ^ 1][2 * tid + 1] = bf2f((unsigned short)(pf1 >> 16));
    }
    pf1 = pf2;
  }
}

extern "C" void kernel_launch(void* const* d_in, const int* in_sizes, int n_in,
                              void* d_out, int out_size, void* d_ws, size_t ws_size,
                              hipStream_t stream) {
  const float* x = (const float*)d_in[0];
  const float* W_slow = (const float*)d_in[1];
  const float* W_out = (const float*)d_in[2];
  const float* gamma = (const float*)d_in[3];
  const float* beta = (const float*)d_in[4];

  char* ws = (char*)d_ws;
  size_t off = 0;
  unsigned short* normed = (unsigned short*)(ws + off); off += (size_t)4096 * 512 * 2;
  unsigned short* Wslow_b = (unsigned short*)(ws + off); off += (size_t)PROJ * 512 * 2;
  unsigned short* Wout_b = (unsigned short*)(ws + off); off += (size_t)512 * 512 * 2;
  unsigned short* qkvb = (unsigned short*)(ws + off); off += (size_t)4096 * PROJ * 2;
  unsigned short* hsb = (unsigned short*)(ws + off); off += (size_t)4096 * 512 * 2;

  hipLaunchKernelGGL(ln_kernel, dim3(1024), dim3(256), 0, stream, x, gamma, beta, normed);
  hipLaunchKernelGGL(cast_kernel, dim3(512), dim3(256), 0, stream, W_slow, Wslow_b, PROJ * 512);
  hipLaunchKernelGGL(cast_kernel, dim3(256), dim3(256), 0, stream, W_out, Wout_b, 512 * 512);
  hipLaunchKernelGGL((gemm_bt<1, 0>), dim3((PROJ + 63) / 64, 4096 / 64), dim3(256), 0, stream,
                     normed, Wslow_b, (void*)qkvb, (const float*)nullptr, 4096, PROJ, 512);
  hipLaunchKernelGGL(scan_kernel, dim3(64), dim3(256), 0, stream, qkvb, hsb);
  hipLaunchKernelGGL((gemm_bt<0, 1>), dim3(512 / 64, 4096 / 64), dim3(256), 0, stream,
                     hsb, Wout_b, d_out, x, 4096, 512, 512);
}

// Round 2
// 1015.007 us; speedup vs baseline: 1.0073x; 1.0073x over previous
//
#include <hip/hip_runtime.h>

#define S_LEN 512
#define BSZ 8
#define NH 8
#define HD 64
#define IN_DIM 512
#define PROJ 2576   // NH*(5*HD+2)
#define SEG 322     // per-head: 5*64+2

typedef __attribute__((ext_vector_type(8))) __bf16 bf16x8;
typedef __attribute__((ext_vector_type(4))) float f32x4;
typedef __attribute__((ext_vector_type(2))) float f32x2;

static __device__ __forceinline__ unsigned short f2bf(float f) {
  unsigned u = __float_as_uint(f);
  unsigned r = (u + 0x7fffu + ((u >> 16) & 1u)) >> 16;
  return (unsigned short)r;
}
static __device__ __forceinline__ float bf2f(unsigned short s) {
  return __uint_as_float(((unsigned)s) << 16);
}

// ---------------- LayerNorm: x (4096x512 f32) -> normed bf16 ----------------
__global__ __launch_bounds__(256) void ln_kernel(const float* __restrict__ x,
                                                 const float* __restrict__ gamma,
                                                 const float* __restrict__ beta,
                                                 unsigned short* __restrict__ out) {
  int wave = threadIdx.x >> 6, lane = threadIdx.x & 63;
  int row = blockIdx.x * 4 + wave;
  const float* xr = x + (size_t)row * IN_DIM + lane * 8;
  float4 a = *(const float4*)xr;
  float4 b = *(const float4*)(xr + 4);
  float vals[8] = {a.x, a.y, a.z, a.w, b.x, b.y, b.z, b.w};
  float s = 0.f, ss = 0.f;
#pragma unroll
  for (int i = 0; i < 8; i++) { s += vals[i]; ss += vals[i] * vals[i]; }
#pragma unroll
  for (int o = 32; o; o >>= 1) { s += __shfl_xor(s, o); ss += __shfl_xor(ss, o); }
  float mu = s * (1.f / 512.f);
  float var = ss * (1.f / 512.f) - mu * mu;
  float rstd = rsqrtf(var + 1e-5f);
  const float* g = gamma + lane * 8;
  const float* be = beta + lane * 8;
  float4 g1 = *(const float4*)g, g2 = *(const float4*)(g + 4);
  float4 b1 = *(const float4*)be, b2 = *(const float4*)(be + 4);
  float gs[8] = {g1.x, g1.y, g1.z, g1.w, g2.x, g2.y, g2.z, g2.w};
  float bs[8] = {b1.x, b1.y, b1.z, b1.w, b2.x, b2.y, b2.z, b2.w};
  union { unsigned short u[8]; uint4 v; } pk;
#pragma unroll
  for (int i = 0; i < 8; i++) pk.u[i] = f2bf((vals[i] - mu) * rstd * gs[i] + bs[i]);
  *(uint4*)(out + (size_t)row * IN_DIM + lane * 8) = pk.v;
}

// ---------------- generic f32 -> bf16 cast ----------------
__global__ void cast_kernel(const float* __restrict__ in, unsigned short* __restrict__ out, int n) {
  int i = blockIdx.x * blockDim.x + threadIdx.x;
  int st = gridDim.x * blockDim.x;
  for (; i < n; i += st) out[i] = f2bf(in[i]);
}

// ---------------- GEMM: C[m][n] = sum_k A[m][k]*B[n][k] (both bf16, K-contig) ----------------
template <int BF16_OUT, int RESID>
__global__ __launch_bounds__(256) void gemm_bt(const unsigned short* __restrict__ A,
                                               const unsigned short* __restrict__ B,
                                               void* __restrict__ Cout,
                                               const float* __restrict__ resid,
                                               int M, int N, int K) {
  __shared__ __align__(16) unsigned short As[64][40];
  __shared__ __align__(16) unsigned short Bs[64][40];
  int tid = threadIdx.x;
  int lane = tid & 63, wave = tid >> 6;
  int m0 = blockIdx.y * 64, n0 = blockIdx.x * 64;
  int srow = tid >> 2, skq = (tid & 3) * 8;
  const unsigned short* Ap = A + (size_t)(m0 + srow) * K + skq;
  const unsigned short* Bp = B + (size_t)(n0 + srow) * K + skq;
  bool bvalid = (n0 + srow) < N;
  f32x4 zero = {0.f, 0.f, 0.f, 0.f};
  f32x4 acc[4];
#pragma unroll
  for (int nt = 0; nt < 4; nt++) acc[nt] = zero;
  int q = lane >> 4, m16 = lane & 15;
  for (int k0 = 0; k0 < K; k0 += 32) {
    uint4 av = *(const uint4*)(Ap + k0);
    uint4 bz = {0u, 0u, 0u, 0u};
    uint4 bv = bvalid ? *(const uint4*)(Bp + k0) : bz;
    *(uint4*)&As[srow][skq] = av;
    *(uint4*)&Bs[srow][skq] = bv;
    __syncthreads();
    bf16x8 af = *(const bf16x8*)&As[wave * 16 + m16][q * 8];
#pragma unroll
    for (int nt = 0; nt < 4; nt++) {
      bf16x8 bfv = *(const bf16x8*)&Bs[nt * 16 + m16][q * 8];
      acc[nt] = __builtin_amdgcn_mfma_f32_16x16x32_bf16(af, bfv, acc[nt], 0, 0, 0);
    }
    __syncthreads();
  }
  int rbase = q * 4;
#pragma unroll
  for (int nt = 0; nt < 4; nt++) {
#pragma unroll
    for (int rr = 0; rr < 4; rr++) {
      int gm = m0 + wave * 16 + rbase + rr;
      int gn = n0 + nt * 16 + m16;
      if (gn < N) {
        float v = acc[nt][rr];
        if (BF16_OUT) {
          ((unsigned short*)Cout)[(size_t)gm * N + gn] = f2bf(v);
        } else {
          float o = v;
          if (RESID) o += resid[(size_t)gm * N + gn];
          ((float*)Cout)[(size_t)gm * N + gn] = o;
        }
      }
    }
  }
}

// ---------------- fused activation + double scan: ONE WAVE per (b,h) ----------------
// Lane r owns full row r of W and row r of R (64+64 f32 in VGPRs). Matvec results
// land whole in lane r -> no reductions, no barriers. k/q/rk/qh broadcast via
// wave-synchronous LDS (write b32, read b128 broadcast). float2 math -> v_pk_fma_f32.
__global__ __launch_bounds__(64) void scan_kernel(const unsigned short* __restrict__ qkvb,
                                                  unsigned short* __restrict__ hs) {
  int bh = blockIdx.x;
  int b = bh >> 3, hh = bh & 7;
  int l = threadIdx.x;

  __shared__ __align__(16) float lk[64];
  __shared__ __align__(16) float lq[64];
  __shared__ __align__(16) float lrk[64];
  __shared__ __align__(16) float lqh[64];

  f32x2 W2[32], R2[32];
#pragma unroll
  for (int j = 0; j < 32; j++) { W2[j] = (f32x2){0.f, 0.f}; R2[j] = (f32x2){0.f, 0.f}; }

  lqh[l] = 1.f / 64.f;  // softmax of h0=0 is uniform
  __builtin_amdgcn_wave_barrier();

  const unsigned short* src = qkvb + (size_t)b * PROJ + hh * SEG;
  const size_t ts = (size_t)BSZ * PROJ;

  // prefetch t = 0
  unsigned short cq = src[l], ck = src[64 + l], cv = src[128 + l];
  unsigned short crk = src[192 + l], crv = src[256 + l];
  unsigned cb = *(const unsigned*)(src + 320);

  for (int t = 0; t < S_LEN; t++) {
    // issue prefetch for t+1 (consumed at top of next iter -> latency hidden by body)
    int tn = (t + 1 < S_LEN) ? (t + 1) : (S_LEN - 1);
    const unsigned short* np = src + (size_t)tn * ts;
    unsigned short nq = np[l], nk = np[64 + l], nv = np[128 + l];
    unsigned short nrk = np[192 + l], nrv = np[256 + l];
    unsigned nb = *(const unsigned*)(np + 320);

    // ---- activations (all in-register, cross-lane via shuffles) ----
    float fq = bf2f(cq), fk = bf2f(ck), fv = bf2f(cv);
    float frk = bf2f(crk), frv = bf2f(crv);
    float beta = __builtin_amdgcn_rcpf(1.f + __expf(-bf2f((unsigned short)(cb & 0xffff))));
    float rbeta = __builtin_amdgcn_rcpf(1.f + __expf(-bf2f((unsigned short)(cb >> 16))));

    float mq = fq, mk = fk, mr = frk;
#pragma unroll
    for (int o = 32; o; o >>= 1) {
      mq = fmaxf(mq, __shfl_xor(mq, o));
      mk = fmaxf(mk, __shfl_xor(mk, o));
      mr = fmaxf(mr, __shfl_xor(mr, o));
    }
    float eq = __expf(fq - mq), ek = __expf(fk - mk), er = __expf(frk - mr);
    float sq = eq, sk = ek, sr = er;
#pragma unroll
    for (int o = 32; o; o >>= 1) {
      sq += __shfl_xor(sq, o);
      sk += __shfl_xor(sk, o);
      sr += __shfl_xor(sr, o);
    }
    float aq = eq * __builtin_amdgcn_rcpf(sq);
    float ak = ek * __builtin_amdgcn_rcpf(sk);
    float ar = er * __builtin_amdgcn_rcpf(sr);

    lk[l] = ak;
    lq[l] = aq;
    lrk[l] = ar;
    __builtin_amdgcn_wave_barrier();  // wave-synchronous: compiler lgkmcnt covers write->read

    const f32x2* k2 = (const f32x2*)lk;
    const f32x2* q2 = (const f32x2*)lq;
    const f32x2* rk2 = (const f32x2*)lrk;
    const f32x2* qh2 = (const f32x2*)lqh;

    // ---- fast weight memory: vold = W k; W += beta(v - vold) k^T; z = W q ----
    f32x2 kk[32];
    f32x2 vo = {0.f, 0.f};
#pragma unroll
    for (int j = 0; j < 32; j++) { kk[j] = k2[j]; vo += W2[j] * kk[j]; }
    float vold = vo.x + vo.y;
    float coef = beta * (fv - vold);
    f32x2 c2 = {coef, coef};
    f32x2 z2 = {0.f, 0.f};
#pragma unroll
    for (int j = 0; j < 32; j++) {
      W2[j] += c2 * kk[j];
      z2 += W2[j] * q2[j];
    }
    float z = z2.x + z2.y;

    // ---- fast rnn: rvold = R rk; R += rbeta(rv - rvold) rk^T; h = z + R qh ----
    f32x2 rvo = {0.f, 0.f};
#pragma unroll
    for (int j = 0; j < 32; j++) { kk[j] = rk2[j]; rvo += R2[j] * kk[j]; }
    float rvold = rvo.x + rvo.y;
    float rcoef = rbeta * (frv - rvold);
    f32x2 rc2 = {rcoef, rcoef};
    f32x2 h2 = {0.f, 0.f};
#pragma unroll
    for (int j = 0; j < 32; j++) {
      R2[j] += rc2 * kk[j];
      h2 += R2[j] * qh2[j];
    }
    float h = z + h2.x + h2.y;

    hs[(size_t)(t * BSZ + b) * 512 + hh * 64 + l] = f2bf(h);

    // ---- softmax(h) -> lqh for next step ----
    float mh = h;
#pragma unroll
    for (int o = 32; o; o >>= 1) mh = fmaxf(mh, __shfl_xor(mh, o));
    float eh = __expf(h - mh);
    float sh = eh;
#pragma unroll
    for (int o = 32; o; o >>= 1) sh += __shfl_xor(sh, o);
    __builtin_amdgcn_wave_barrier();  // qh2 reads above complete before overwrite (in-order DS)
    lqh[l] = eh * __builtin_amdgcn_rcpf(sh);
    __builtin_amdgcn_wave_barrier();

    cq = nq; ck = nk; cv = nv; crk = nrk; crv = nrv; cb = nb;
  }
}

extern "C" void kernel_launch(void* const* d_in, const int* in_sizes, int n_in,
                              void* d_out, int out_size, void* d_ws, size_t ws_size,
                              hipStream_t stream) {
  const float* x = (const float*)d_in[0];
  const float* W_slow = (const float*)d_in[1];
  const float* W_out = (const float*)d_in[2];
  const float* gamma = (const float*)d_in[3];
  const float* beta = (const float*)d_in[4];

  char* ws = (char*)d_ws;
  size_t off = 0;
  unsigned short* normed = (unsigned short*)(ws + off); off += (size_t)4096 * 512 * 2;
  unsigned short* Wslow_b = (unsigned short*)(ws + off); off += (size_t)PROJ * 512 * 2;
  unsigned short* Wout_b = (unsigned short*)(ws + off); off += (size_t)512 * 512 * 2;
  unsigned short* qkvb = (unsigned short*)(ws + off); off += (size_t)4096 * PROJ * 2;
  unsigned short* hsb = (unsigned short*)(ws + off); off += (size_t)4096 * 512 * 2;

  hipLaunchKernelGGL(ln_kernel, dim3(1024), dim3(256), 0, stream, x, gamma, beta, normed);
  hipLaunchKernelGGL(cast_kernel, dim3(512), dim3(256), 0, stream, W_slow, Wslow_b, PROJ * 512);
  hipLaunchKernelGGL(cast_kernel, dim3(256), dim3(256), 0, stream, W_out, Wout_b, 512 * 512);
  hipLaunchKernelGGL((gemm_bt<1, 0>), dim3((PROJ + 63) / 64, 4096 / 64), dim3(256), 0, stream,
                     normed, Wslow_b, (void*)qkvb, (const float*)nullptr, 4096, PROJ, 512);
  hipLaunchKernelGGL(scan_kernel, dim3(64), dim3(64), 0, stream, qkvb, hsb);
  hipLaunchKernelGGL((gemm_bt<0, 1>), dim3(512 / 64, 4096 / 64), dim3(256), 0, stream,
                     hsb, Wout_b, d_out, x, 4096, 512, 512);
}

// Round 3
// 513.506 us; speedup vs baseline: 1.9910x; 1.9766x over previous
//
#include <hip/hip_runtime.h>

#define S_LEN 512
#define BSZ 8
#define NH 8
#define HD 64
#define IN_DIM 512
#define PROJ 2576   // NH*(5*HD+2)
#define SEG 322     // per-head: 5*64+2
#define AST 200     // act row stride in f32: q64,k64,rk64,beta,rbeta

typedef __attribute__((ext_vector_type(8))) __bf16 bf16x8;
typedef __attribute__((ext_vector_type(4))) float f32x4;
typedef __attribute__((ext_vector_type(2))) float f32x2;

static __device__ __forceinline__ unsigned short f2bf(float f) {
  unsigned u = __float_as_uint(f);
  unsigned r = (u + 0x7fffu + ((u >> 16) & 1u)) >> 16;
  return (unsigned short)r;
}
static __device__ __forceinline__ float bf2f(unsigned short s) {
  return __uint_as_float(((unsigned)s) << 16);
}

// ---------------- LayerNorm: x (4096x512 f32) -> normed bf16 ----------------
__global__ __launch_bounds__(256) void ln_kernel(const float* __restrict__ x,
                                                 const float* __restrict__ gamma,
                                                 const float* __restrict__ beta,
                                                 unsigned short* __restrict__ out) {
  int wave = threadIdx.x >> 6, lane = threadIdx.x & 63;
  int row = blockIdx.x * 4 + wave;
  const float* xr = x + (size_t)row * IN_DIM + lane * 8;
  float4 a = *(const float4*)xr;
  float4 b = *(const float4*)(xr + 4);
  float vals[8] = {a.x, a.y, a.z, a.w, b.x, b.y, b.z, b.w};
  float s = 0.f, ss = 0.f;
#pragma unroll
  for (int i = 0; i < 8; i++) { s += vals[i]; ss += vals[i] * vals[i]; }
#pragma unroll
  for (int o = 32; o; o >>= 1) { s += __shfl_xor(s, o); ss += __shfl_xor(ss, o); }
  float mu = s * (1.f / 512.f);
  float var = ss * (1.f / 512.f) - mu * mu;
  float rstd = rsqrtf(var + 1e-5f);
  const float* g = gamma + lane * 8;
  const float* be = beta + lane * 8;
  float4 g1 = *(const float4*)g, g2 = *(const float4*)(g + 4);
  float4 b1 = *(const float4*)be, b2 = *(const float4*)(be + 4);
  float gs[8] = {g1.x, g1.y, g1.z, g1.w, g2.x, g2.y, g2.z, g2.w};
  float bs[8] = {b1.x, b1.y, b1.z, b1.w, b2.x, b2.y, b2.z, b2.w};
  union { unsigned short u[8]; uint4 v; } pk;
#pragma unroll
  for (int i = 0; i < 8; i++) pk.u[i] = f2bf((vals[i] - mu) * rstd * gs[i] + bs[i]);
  *(uint4*)(out + (size_t)row * IN_DIM + lane * 8) = pk.v;
}

// ---------------- generic f32 -> bf16 cast ----------------
__global__ void cast_kernel(const float* __restrict__ in, unsigned short* __restrict__ out, int n) {
  int i = blockIdx.x * blockDim.x + threadIdx.x;
  int st = gridDim.x * blockDim.x;
  for (; i < n; i += st) out[i] = f2bf(in[i]);
}

// ---------------- GEMM: C[m][n] = sum_k A[m][k]*B[n][k] (both bf16, K-contig) ----------------
template <int BF16_OUT, int RESID>
__global__ __launch_bounds__(256) void gemm_bt(const unsigned short* __restrict__ A,
                                               const unsigned short* __restrict__ B,
                                               void* __restrict__ Cout,
                                               const float* __restrict__ resid,
                                               int M, int N, int K) {
  __shared__ __align__(16) unsigned short As[64][40];
  __shared__ __align__(16) unsigned short Bs[64][40];
  int tid = threadIdx.x;
  int lane = tid & 63, wave = tid >> 6;
  int m0 = blockIdx.y * 64, n0 = blockIdx.x * 64;
  int srow = tid >> 2, skq = (tid & 3) * 8;
  const unsigned short* Ap = A + (size_t)(m0 + srow) * K + skq;
  const unsigned short* Bp = B + (size_t)(n0 + srow) * K + skq;
  bool bvalid = (n0 + srow) < N;
  f32x4 zero = {0.f, 0.f, 0.f, 0.f};
  f32x4 acc[4];
#pragma unroll
  for (int nt = 0; nt < 4; nt++) acc[nt] = zero;
  int q = lane >> 4, m16 = lane & 15;
  for (int k0 = 0; k0 < K; k0 += 32) {
    uint4 av = *(const uint4*)(Ap + k0);
    uint4 bz = {0u, 0u, 0u, 0u};
    uint4 bv = bvalid ? *(const uint4*)(Bp + k0) : bz;
    *(uint4*)&As[srow][skq] = av;
    *(uint4*)&Bs[srow][skq] = bv;
    __syncthreads();
    bf16x8 af = *(const bf16x8*)&As[wave * 16 + m16][q * 8];
#pragma unroll
    for (int nt = 0; nt < 4; nt++) {
      bf16x8 bfv = *(const bf16x8*)&Bs[nt * 16 + m16][q * 8];
      acc[nt] = __builtin_amdgcn_mfma_f32_16x16x32_bf16(af, bfv, acc[nt], 0, 0, 0);
    }
    __syncthreads();
  }
  int rbase = q * 4;
#pragma unroll
  for (int nt = 0; nt < 4; nt++) {
#pragma unroll
    for (int rr = 0; rr < 4; rr++) {
      int gm = m0 + wave * 16 + rbase + rr;
      int gn = n0 + nt * 16 + m16;
      if (gn < N) {
        float v = acc[nt][rr];
        if (BF16_OUT) {
          ((unsigned short*)Cout)[(size_t)gm * N + gn] = f2bf(v);
        } else {
          float o = v;
          if (RESID) o += resid[(size_t)gm * N + gn];
          ((float*)Cout)[(size_t)gm * N + gn] = o;
        }
      }
    }
  }
}

// ---------------- parallel activations: softmax(q,k,rk), sigmoid(betas) -> f32 ----------------
// One wave per (m = t*8+b, h). act[bh][t][AST]: [0:64) q, [64:128) k, [128:192) rk, [192] beta, [193] rbeta.
__global__ __launch_bounds__(256) void act_kernel(const unsigned short* __restrict__ qkvb,
                                                  float* __restrict__ act) {
  int gw = blockIdx.x * 4 + (threadIdx.x >> 6);
  int l = threadIdx.x & 63;
  int m = gw >> 3, hh = gw & 7;
  int t = m >> 3, b = m & 7;
  const unsigned short* src = qkvb + (size_t)m * PROJ + hh * SEG;
  float fq = bf2f(src[l]);
  float fk = bf2f(src[64 + l]);
  float fr = bf2f(src[192 + l]);
  float mq = fq, mk = fk, mr = fr;
#pragma unroll
  for (int o = 32; o; o >>= 1) {
    mq = fmaxf(mq, __shfl_xor(mq, o));
    mk = fmaxf(mk, __shfl_xor(mk, o));
    mr = fmaxf(mr, __shfl_xor(mr, o));
  }
  float eq = __expf(fq - mq), ek = __expf(fk - mk), er = __expf(fr - mr);
  float sq = eq, sk = ek, sr = er;
#pragma unroll
  for (int o = 32; o; o >>= 1) {
    sq += __shfl_xor(sq, o);
    sk += __shfl_xor(sk, o);
    sr += __shfl_xor(sr, o);
  }
  int bh = b * 8 + hh;
  float* dst = act + ((size_t)bh * S_LEN + t) * AST;
  dst[l] = eq * __builtin_amdgcn_rcpf(sq);
  dst[64 + l] = ek * __builtin_amdgcn_rcpf(sk);
  dst[128 + l] = er * __builtin_amdgcn_rcpf(sr);
  if (l < 2) {
    float xv = bf2f(src[320 + l]);
    dst[192 + l] = __builtin_amdgcn_rcpf(1.f + __expf(-xv));
  }
}

// ---------------- scan: producer/consumer waves, zero cross-lane shuffles ----------------
// Block = 128 threads = 2 waves per (b,h). Wave0: delta-rule W-scan (emits z to LDS).
// Wave1: recurrent R-scan (consumes z). Lane l owns full row l of its matrix (f32x2[32]).
// h-softmax: per-lane exp written to LDS; sum folded into the R.eh matvec (no reduction).
__global__ __launch_bounds__(128) void scan_kernel(const unsigned short* __restrict__ qkvb,
                                                   const float* __restrict__ act,
                                                   unsigned short* __restrict__ hs) {
  int bh = blockIdx.x;
  int b = bh >> 3, hh = bh & 7;
  int tid = threadIdx.x, l = tid & 63, w = tid >> 6;

  __shared__ __align__(16) float stage[2][AST];
  __shared__ __align__(16) float zbuf[2][64];
  __shared__ __align__(16) float ehb[64];

  const float* arow = act + (size_t)bh * S_LEN * AST;
  // wave0 reads v (offset 128), wave1 reads rv (offset 256) from qkvb
  const unsigned short* vsrc = qkvb + (size_t)b * PROJ + hh * SEG + (w ? 256 : 128);
  const size_t ts = (size_t)BSZ * PROJ;

  f32x2 M[32];
#pragma unroll
  for (int j = 0; j < 32; j++) M[j] = (f32x2){0.f, 0.f};

  // stage t=0 cooperatively; init eh (softmax of h0=0 -> uniform; sum handled naturally)
  if (w == 0) {
    stage[0][l] = arow[l];
    stage[0][64 + l] = arow[64 + l];
  } else {
    stage[0][128 + l] = arow[128 + l];
    float bb = arow[192 + (l & 1)];
    if (l < 2) stage[0][192 + l] = bb;
    ehb[l] = 1.f;
  }
  float cv = bf2f(vsrc[l]);  // v_0 (wave0) or rv_0 (wave1)
  __syncthreads();

  unsigned short* hdst = hs + (size_t)b * 512 + hh * 64 + l;

  for (int t = 0; t < S_LEN; t++) {
    int buf = t & 1;
    int tn = (t + 1 < S_LEN) ? (t + 1) : t;
    // prefetch t+1 into registers (ds_write'd at iteration end)
    const float* rn = arow + (size_t)tn * AST;
    float nv = bf2f(vsrc[(size_t)tn * ts + l]);
    float p0, p1;
    if (w == 0) {
      p0 = rn[l];
      p1 = rn[64 + l];
    } else {
      p0 = rn[128 + l];
      p1 = rn[192 + (l & 1)];
    }

    const f32x2* s2 = (const f32x2*)stage[buf];
    float hp = 0.f, sm = 0.f;

    if (w == 0) {
      // ---- W-scan: vold = W.k; W += beta(v-vold)k^T; z = W.q ----
      f32x2 kk[32];
#pragma unroll
      for (int j = 0; j < 32; j++) kk[j] = s2[32 + j];  // k
      f32x2 a0 = {0.f, 0.f}, a1 = {0.f, 0.f}, a2 = {0.f, 0.f}, a3 = {0.f, 0.f};
#pragma unroll
      for (int j = 0; j < 32; j += 4) {
        a0 += M[j] * kk[j];
        a1 += M[j + 1] * kk[j + 1];
        a2 += M[j + 2] * kk[j + 2];
        a3 += M[j + 3] * kk[j + 3];
      }
      f32x2 vo = (a0 + a1) + (a2 + a3);
      float vold = vo.x + vo.y;
      float beta = stage[buf][192];
      float coef = beta * (cv - vold);
      f32x2 c2 = {coef, coef};
      a0 = a1 = a2 = a3 = (f32x2){0.f, 0.f};
#pragma unroll
      for (int j = 0; j < 32; j += 4) {
        M[j] += c2 * kk[j];           a0 += M[j] * s2[j];
        M[j + 1] += c2 * kk[j + 1];   a1 += M[j + 1] * s2[j + 1];
        M[j + 2] += c2 * kk[j + 2];   a2 += M[j + 2] * s2[j + 2];
        M[j + 3] += c2 * kk[j + 3];   a3 += M[j + 3] * s2[j + 3];
      }
      f32x2 zo = (a0 + a1) + (a2 + a3);
      zbuf[buf][l] = zo.x + zo.y;
    } else {
      // ---- R-scan: rvold = R.rk; R += rbeta(rv-rvold)rk^T; hp = R.eh, sm = sum(eh) ----
      f32x2 kk[32];
#pragma unroll
      for (int j = 0; j < 32; j++) kk[j] = s2[64 + j];  // rk
      f32x2 a0 = {0.f, 0.f}, a1 = {0.f, 0.f}, a2 = {0.f, 0.f}, a3 = {0.f, 0.f};
#pragma unroll
      for (int j = 0; j < 32; j += 4) {
        a0 += M[j] * kk[j];
        a1 += M[j + 1] * kk[j + 1];
        a2 += M[j + 2] * kk[j + 2];
        a3 += M[j + 3] * kk[j + 3];
      }
      f32x2 vo = (a0 + a1) + (a2 + a3);
      float rvold = vo.x + vo.y;
      float rbeta = stage[buf][193];
      float rcoef = rbeta * (cv - rvold);
      f32x2 c2 = {rcoef, rcoef};
      const f32x2* e2 = (const f32x2*)ehb;
      f32x2 s0 = {0.f, 0.f}, s1 = {0.f, 0.f}, s2a = {0.f, 0.f}, s3 = {0.f, 0.f};
      a0 = a1 = a2 = a3 = (f32x2){0.f, 0.f};
#pragma unroll
      for (int j = 0; j < 32; j += 4) {
        f32x2 e0 = e2[j], e1 = e2[j + 1], e2v = e2[j + 2], e3 = e2[j + 3];
        M[j] += c2 * kk[j];           a0 += M[j] * e0;       s0 += e0;
        M[j + 1] += c2 * kk[j + 1];   a1 += M[j + 1] * e1;   s1 += e1;
        M[j + 2] += c2 * kk[j + 2];   a2 += M[j + 2] * e2v;  s2a += e2v;
        M[j + 3] += c2 * kk[j + 3];   a3 += M[j + 3] * e3;   s3 += e3;
      }
      f32x2 ho = (a0 + a1) + (a2 + a3);
      f32x2 so = (s0 + s1) + (s2a + s3);
      hp = ho.x + ho.y;
      sm = so.x + so.y;
    }

    // stage t+1 for both waves
    {
      float* st = stage[buf ^ 1];
      if (w == 0) {
        st[l] = p0;
        st[64 + l] = p1;
      } else {
        st[128 + l] = p0;
        if (l < 2) st[192 + l] = p1;
      }
    }
    __syncthreads();  // z, eh-era, and next stage visible

    if (w == 1) {
      float z = zbuf[buf][l];
      float h = z + hp * __builtin_amdgcn_rcpf(sm);
      hdst[(size_t)t * BSZ * 512] = f2bf(h);
      // shift-invariant: exp(h-20) keeps qh = eh/sum exact, guards overflow
      ehb[l] = __expf(h - 20.f);
    }
    cv = nv;
  }
}

extern "C" void kernel_launch(void* const* d_in, const int* in_sizes, int n_in,
                              void* d_out, int out_size, void* d_ws, size_t ws_size,
                              hipStream_t stream) {
  const float* x = (const float*)d_in[0];
  const float* W_slow = (const float*)d_in[1];
  const float* W_out = (const float*)d_in[2];
  const float* gamma = (const float*)d_in[3];
  const float* beta = (const float*)d_in[4];

  char* ws = (char*)d_ws;
  size_t off = 0;
  unsigned short* normed = (unsigned short*)(ws + off); off += (size_t)4096 * 512 * 2;
  unsigned short* Wslow_b = (unsigned short*)(ws + off); off += (size_t)PROJ * 512 * 2;
  unsigned short* Wout_b = (unsigned short*)(ws + off); off += (size_t)512 * 512 * 2;
  unsigned short* qkvb = (unsigned short*)(ws + off); off += (size_t)4096 * PROJ * 2;
  float* act = (float*)(ws + off); off += (size_t)64 * S_LEN * AST * 4;
  unsigned short* hsb = normed;  // normed is dead after gemm1; reuse for hs

  hipLaunchKernelGGL(ln_kernel, dim3(1024), dim3(256), 0, stream, x, gamma, beta, normed);
  hipLaunchKernelGGL(cast_kernel, dim3(512), dim3(256), 0, stream, W_slow, Wslow_b, PROJ * 512);
  hipLaunchKernelGGL(cast_kernel, dim3(256), dim3(256), 0, stream, W_out, Wout_b, 512 * 512);
  hipLaunchKernelGGL((gemm_bt<1, 0>), dim3((PROJ + 63) / 64, 4096 / 64), dim3(256), 0, stream,
                     normed, Wslow_b, (void*)qkvb, (const float*)nullptr, 4096, PROJ, 512);
  hipLaunchKernelGGL(act_kernel, dim3(8192), dim3(256), 0, stream, qkvb, act);
  hipLaunchKernelGGL(scan_kernel, dim3(64), dim3(128), 0, stream, qkvb, act, hsb);
  hipLaunchKernelGGL((gemm_bt<0, 1>), dim3(512 / 64, 4096 / 64), dim3(256), 0, stream,
                     hsb, Wout_b, d_out, x, 4096, 512, 512);
}